// Round 10
// baseline (114.802 us; speedup 1.0000x reference)
//
#include <hip/hip_runtime.h>
#include <hip/hip_bf16.h>
#include <math.h>

// Problem constants (fixed by setup_inputs)
constexpr int kB = 32;         // batch
constexpr int kS = 128;        // seq len
constexpr int kD = 256;        // hidden
constexpr int kK = 8;          // window
constexpr int kNPair = 2104;   // pairs with |j-i|<=8
constexpr int kInDim = 576;    // 2D + P
constexpr int kRS = 260;       // padded f32 LDS row stride

typedef __attribute__((ext_vector_type(8))) short short8;   // 8 bf16
typedef __attribute__((ext_vector_type(4))) float f32x4;    // MFMA C/D frag

// f32 -> bf16, round-to-nearest-even
__device__ inline ushort f2b(float f) {
  union { float f; uint u; } v; v.f = f;
  uint r = v.u + 0x7FFF + ((v.u >> 16) & 1);
  return (ushort)(r >> 16);
}
__device__ inline short8 pack8(float4 p, float4 q) {
  union { short8 s; __hip_bfloat162 h[4]; } u;
  u.h[0] = __float22bfloat162_rn(make_float2(p.x, p.y));
  u.h[1] = __float22bfloat162_rn(make_float2(p.z, p.w));
  u.h[2] = __float22bfloat162_rn(make_float2(q.x, q.y));
  u.h[3] = __float22bfloat162_rn(make_float2(q.z, q.w));
  return u.s;
}

// ---------------------------------------------------------------------------
// prep: repack Wcat[512 cols][256 K] (f32 rows of W1) into FRAGMENT-LINEAR
// bf16: Wb[ct=col/16][kk=K/32][lane][8] where lane = ((K>>3)&3)<<4 | (col&15).
// A wave's B-fragment load becomes one contiguous 1KB burst.
// ---------------------------------------------------------------------------
__global__ __launch_bounds__(256) void prep(const float* __restrict__ W1,
                                            ushort* __restrict__ Wb) {
  const int chunk = blockIdx.x * 256 + threadIdx.x;   // [0, 16384)
  const int c = chunk >> 5;          // output col 0..511
  const int k8 = chunk & 31;         // 8-elem K chunk
  const float* src = W1 + (c & 255) * kInDim + ((c < 256) ? 0 : 256) + k8 * 8;
  float4 p = *(const float4*)src;
  float4 q = *(const float4*)(src + 4);
  short8 v = pack8(p, q);
  const int frag = (c >> 4) * 8 + (k8 >> 2);
  const int ln = ((k8 & 3) << 4) | (c & 15);
  *(short8*)(Wb + frag * 512 + ln * 8) = v;
}

// ---------------------------------------------------------------------------
// fused: 512 blocks (b = blk>>4, i0 = (blk&15)*8) x 512 threads = 8 waves;
// 72KB LDS -> 2 blocks/CU -> 4 waves/SIMD. TWO barriers total.
//  phase0: rpe_eff table + stage own 24-row H window (f2b, swizzled LDS)
//  phase1: R-build (dot-64s) + GEMM C[32][512] (A from LDS, B coalesced
//          frag bursts from Wb, 64 MFMA/wave) -> sU/sV/sR
//  phase2: pair scores (32 x 16-lane groups, 4-5 slots each)
// ---------------------------------------------------------------------------
__global__ __launch_bounds__(512, 4) void fused(
    const float* __restrict__ H, const float* __restrict__ pos_emb,
    const float* __restrict__ W1, const float* __restrict__ b1,
    const ushort* __restrict__ Wb,
    const float* __restrict__ ln_g, const float* __restrict__ ln_b,
    const float* __restrict__ W2, const float* __restrict__ b2,
    float* __restrict__ out) {
  __shared__ __align__(16) ushort sH[32 * 256];   // 16 KB bf16, XOR-swizzled
  __shared__ float sRpe[17 * 64];                 // 4.25 KB
  __shared__ float sR[17 * kRS];                  // 17.7 KB
  __shared__ float sU[8 * kRS];                   // 8.3 KB
  __shared__ float sV[24 * kRS];                  // 25 KB

  const int tid = threadIdx.x;
  const int lane = tid & 63;
  const int w = tid >> 6;            // wave 0..7
  const int b = blockIdx.x >> 4;
  const int i0 = (blockIdx.x & 15) << 3;
  const int ws = (i0 - 8 > 0) ? (i0 - 8) : 0;            // multiple of 8
  const int we = (i0 + 15 < kS - 1) ? (i0 + 15) : (kS - 1);
  const int nrows = we - ws + 1;     // 16 or 24
  const int oi = i0 - ws;            // 0 or 8

  // ---- phase 0a: rpe_eff[t][p] = sum_u (128-|u-8|) exp(-(t-u)^2) pe[u][p] ----
  if (tid < 272) {
    const int t = tid >> 4, p4 = (tid & 15) << 2;
    float a0 = 0.f, a1 = 0.f, a2 = 0.f, a3 = 0.f;
#pragma unroll
    for (int u = 0; u < 17; ++u) {
      int du = t - u, au = u - kK; if (au < 0) au = -au;
      float wt = __expf((float)(-(du * du))) * (float)(kS - au);
      float4 pe = *(const float4*)(pos_emb + u * 64 + p4);
      a0 += wt * pe.x; a1 += wt * pe.y; a2 += wt * pe.z; a3 += wt * pe.w;
    }
    sRpe[t * 64 + p4] = a0; sRpe[t * 64 + p4 + 1] = a1;
    sRpe[t * 64 + p4 + 2] = a2; sRpe[t * 64 + p4 + 3] = a3;
  }
  // ---- phase 0b: stage H window (<=24 rows) as bf16, row-XOR swizzle ----
  for (int idx = tid; idx < nrows * 64; idx += 512) {
    const int rw = idx >> 6, kq = (idx & 63) << 2;
    float4 a = *(const float4*)(H + (b * kS + ws + rw) * kD + kq);
    ushort4 u; u.x = f2b(a.x); u.y = f2b(a.y); u.z = f2b(a.z); u.w = f2b(a.w);
    *(ushort4*)&sH[rw * 256 + (kq ^ ((rw & 7) << 3))] = u;
  }
  __syncthreads();

  // ---- phase 1a: R[t][d] = rpe_eff[t] . W1c[d] + b1[d] ----
  {
    const int d = tid & 255;
    const int th = tid >> 8;               // 0: t 0..8, 1: t 9..16
    float wc[64];
    const float* wr = W1 + d * kInDim + 512;
#pragma unroll
    for (int q = 0; q < 16; ++q) {
      float4 t4 = *(const float4*)(wr + q * 4);
      wc[q * 4 + 0] = t4.x; wc[q * 4 + 1] = t4.y;
      wc[q * 4 + 2] = t4.z; wc[q * 4 + 3] = t4.w;
    }
    const float bd = b1[d];
    const int tb2 = th * 9, te2 = th ? 17 : 9;
    for (int t = tb2; t < te2; ++t) {
      float s = 0.f;
#pragma unroll
      for (int p = 0; p < 64; ++p) s += wc[p] * sRpe[t * 64 + p];
      sR[t * kRS + d] = s + bd;
    }
  }
  // ---- phase 1b: GEMM C[32][512]; wave w -> cols [w*64, w*64+64) ----
  {
    const int lr = lane & 15;
    const int lk = (lane >> 4) << 3;
    const int swz = (lr & 7) << 3;
    f32x4 acc[2][4] = {{{0,0,0,0},{0,0,0,0},{0,0,0,0},{0,0,0,0}},
                       {{0,0,0,0},{0,0,0,0},{0,0,0,0},{0,0,0,0}}};
#pragma unroll
    for (int kk = 0; kk < 8; ++kk) {
      const int k0 = (kk << 5) + lk;
      short8 a0 = *(const short8*)(const void*)&sH[lr * 256 + (k0 ^ swz)];
      short8 a1 = *(const short8*)(const void*)&sH[(16 + lr) * 256 + (k0 ^ swz)];
#pragma unroll
      for (int ci = 0; ci < 4; ++ci) {
        const int ct = (w << 2) + ci;
        short8 bf = *(const short8*)(const void*)(Wb + (ct * 8 + kk) * 512 + lane * 8);
        acc[0][ci] = __builtin_amdgcn_mfma_f32_16x16x32_bf16(a0, bf, acc[0][ci], 0, 0, 0);
        acc[1][ci] = __builtin_amdgcn_mfma_f32_16x16x32_bf16(a1, bf, acc[1][ci], 0, 0, 0);
      }
    }
    const int r0 = (lane >> 4) << 2;
#pragma unroll
    for (int m = 0; m < 2; ++m)
#pragma unroll
      for (int ci = 0; ci < 4; ++ci) {
        const int cg = ((w << 2) + ci) * 16 + (lane & 15);
#pragma unroll
        for (int r = 0; r < 4; ++r) {
          const int rw = (m << 4) + r0 + r;
          const float val = acc[m][ci][r];
          if (cg < kD) {
            unsigned ur = (unsigned)(rw - oi);
            if (ur < 8u) sU[ur * kRS + cg] = val;
          } else if (rw < nrows) {
            sV[rw * kRS + (cg - kD)] = val;
          }
        }
      }
  }
  __syncthreads();

  // ---- phase 2: pair scores. group g: ir = g>>2, t-quarter qq = g&3 ----
  const int g = tid >> 4, l16 = tid & 15;
  const int ir = g >> 2, qq = g & 3;
  const int tb = qq * 4 + (qq > 0);     // 0,5,9,13
  const int te = qq * 4 + 5;            // 5,9,13,17
  const int i = i0 + ir;

  float ureg[16];
#pragma unroll
  for (int q = 0; q < 4; ++q) {
    float4 u4 = *(const float4*)&sU[ir * kRS + (q << 6) + (l16 << 2)];
    ureg[q * 4 + 0] = u4.x; ureg[q * 4 + 1] = u4.y;
    ureg[q * 4 + 2] = u4.z; ureg[q * 4 + 3] = u4.w;
  }
  float4 Gp[4], Bp[4], Wp[4];
#pragma unroll
  for (int q = 0; q < 4; ++q) {
    const int d = (q << 6) + (l16 << 2);
    Gp[q] = *(const float4*)(ln_g + d);
    Bp[q] = *(const float4*)(ln_b + d);
    Wp[q] = *(const float4*)(W2 + d);
  }
  const float bias2 = b2[0];

  int start_i;
  if (i <= 8)        start_i = (i * i + 17 * i) / 2;
  else if (i <= 120) start_i = 100 + (i - 8) * 17;
  else { int mm = i - 120; start_i = 2004 + 16 * mm - (mm * (mm - 1)) / 2; }
  const int lower = (i - kK > 0) ? (i - kK) : 0;

  for (int t = tb; t < te; ++t) {
    const int j = i - kK + t;
    if (j < 0 || j >= kS) continue;     // group-uniform
    const int p = start_i + (j - lower);
    const float* Vr = &sV[(j - ws) * kRS];
    const float* Rr = &sR[t * kRS];

    float h[16]; float ssum = 0.f, qsum = 0.f;
#pragma unroll
    for (int q = 0; q < 4; ++q) {
      const int d = (q << 6) + (l16 << 2);
      float4 v4 = *(const float4*)(Vr + d);
      float4 r4 = *(const float4*)(Rr + d);
      float h0 = ureg[q * 4 + 0] + v4.x + r4.x;
      float h1 = ureg[q * 4 + 1] + v4.y + r4.y;
      float h2 = ureg[q * 4 + 2] + v4.z + r4.z;
      float h3 = ureg[q * 4 + 3] + v4.w + r4.w;
      h[q * 4 + 0] = h0; h[q * 4 + 1] = h1; h[q * 4 + 2] = h2; h[q * 4 + 3] = h3;
      ssum += h0 + h1 + h2 + h3;
      qsum += h0 * h0 + h1 * h1 + h2 * h2 + h3 * h3;
    }
#pragma unroll
    for (int off = 8; off > 0; off >>= 1) {
      ssum += __shfl_xor(ssum, off);
      qsum += __shfl_xor(qsum, off);
    }
    const float mu = ssum * (1.0f / kD);
    const float var = qsum * (1.0f / kD) - mu * mu;
    const float rs = rsqrtf(var + 1e-5f);
    float dot = 0.f;
#pragma unroll
    for (int q = 0; q < 4; ++q) {
      float y0 = (h[q * 4 + 0] - mu) * rs * Gp[q].x + Bp[q].x;
      float y1 = (h[q * 4 + 1] - mu) * rs * Gp[q].y + Bp[q].y;
      float y2 = (h[q * 4 + 2] - mu) * rs * Gp[q].z + Bp[q].z;
      float y3 = (h[q * 4 + 3] - mu) * rs * Gp[q].w + Bp[q].w;
      y0 = y0 > 0.f ? y0 : (__expf(y0) - 1.0f);   // elu (alpha=1)
      y1 = y1 > 0.f ? y1 : (__expf(y1) - 1.0f);
      y2 = y2 > 0.f ? y2 : (__expf(y2) - 1.0f);
      y3 = y3 > 0.f ? y3 : (__expf(y3) - 1.0f);
      dot += y0 * Wp[q].x + y1 * Wp[q].y + y2 * Wp[q].z + y3 * Wp[q].w;
    }
#pragma unroll
    for (int off = 8; off > 0; off >>= 1) dot += __shfl_xor(dot, off);

    if (l16 == 0) {
      out[b * kNPair + p] = dot + bias2;
      if (b == 0) {
        float* po = out + kB * kNPair;  // positions read back as f32
        po[2 * p + 0] = (float)(i + 1);
        po[2 * p + 1] = (float)(j + 1);
      }
    }
  }
}

// ---------------------------------------------------------------------------
extern "C" void kernel_launch(void* const* d_in, const int* in_sizes, int n_in,
                              void* d_out, int out_size, void* d_ws, size_t ws_size,
                              hipStream_t stream) {
  (void)in_sizes; (void)n_in; (void)ws_size; (void)out_size;
  const float* H       = (const float*)d_in[0];  // [32,128,256]
  const float* pos_emb = (const float*)d_in[1];  // [17,64]
  const float* W1      = (const float*)d_in[2];  // [256,576]
  const float* b1      = (const float*)d_in[3];  // [256]
  const float* ln_g    = (const float*)d_in[4];  // [256]
  const float* ln_b    = (const float*)d_in[5];  // [256]
  const float* W2      = (const float*)d_in[6];  // [1,256]
  const float* b2      = (const float*)d_in[7];  // [1]
  float* out = (float*)d_out;

  ushort* Wb = (ushort*)d_ws;          // [32][8][64][8] bf16 fragment-linear

  prep<<<64, 256, 0, stream>>>(W1, Wb);
  fused<<<kB * 16, 512, 0, stream>>>(H, pos_emb, W1, b1, Wb,
                                     ln_g, ln_b, W2, b2, out);
}

// Round 11
// 44.175 us; speedup vs baseline: 2.5988x; 2.5988x over previous
//
#include <hip/hip_runtime.h>
#include <hip/hip_bf16.h>
#include <math.h>

// Problem constants (fixed by setup_inputs)
constexpr int kB = 32;         // batch
constexpr int kS = 128;        // seq len
constexpr int kD = 256;        // hidden
constexpr int kK = 8;          // window
constexpr int kNPair = 2104;   // pairs with |j-i|<=8
constexpr int kInDim = 576;    // 2D + P
constexpr int kRS = 260;       // padded f32 LDS row stride

typedef __attribute__((ext_vector_type(8))) short short8;   // 8 bf16
typedef __attribute__((ext_vector_type(4))) float f32x4;    // MFMA C/D frag

// f32 -> bf16, round-to-nearest-even
__device__ inline ushort f2b(float f) {
  union { float f; uint u; } v; v.f = f;
  uint r = v.u + 0x7FFF + ((v.u >> 16) & 1);
  return (ushort)(r >> 16);
}
__device__ inline short8 pack8(float4 p, float4 q) {
  union { short8 s; __hip_bfloat162 h[4]; } u;
  u.h[0] = __float22bfloat162_rn(make_float2(p.x, p.y));
  u.h[1] = __float22bfloat162_rn(make_float2(p.z, p.w));
  u.h[2] = __float22bfloat162_rn(make_float2(q.x, q.y));
  u.h[3] = __float22bfloat162_rn(make_float2(q.z, q.w));
  return u.s;
}

// ---------------------------------------------------------------------------
// prep: blocks 0..63 repack Wcat[512 cols][256 K] into FRAGMENT-LINEAR bf16:
//   Wb[ct=col/16][kk=K/32][lane][8], lane = ((K>>3)&3)<<4 | (col&15)
//   -> a wave's B-fragment load is one contiguous 1KB burst.
// block 64: Rg[17][256] f32 = sum_u (128-|u-8|)exp(-(t-u)^2)(pe[u].W1c[d]) + b1[d]
// (256 threads, unconstrained registers -> w[64] cache is register-resident.)
// ---------------------------------------------------------------------------
__global__ __launch_bounds__(256) void prep(
    const float* __restrict__ W1, const float* __restrict__ pos_emb,
    const float* __restrict__ b1,
    ushort* __restrict__ Wb, float* __restrict__ Rg) {
  const int blk = blockIdx.x, tid = threadIdx.x;
  if (blk < 64) {
    const int chunk = blk * 256 + tid;   // [0, 16384)
    const int c = chunk >> 5;            // output col 0..511
    const int k8 = chunk & 31;           // 8-elem K chunk
    const float* src = W1 + (c & 255) * kInDim + ((c < 256) ? 0 : 256) + k8 * 8;
    float4 p = *(const float4*)src;
    float4 q = *(const float4*)(src + 4);
    short8 v = pack8(p, q);
    const int frag = (c >> 4) * 8 + (k8 >> 2);
    const int ln = ((k8 & 3) << 4) | (c & 15);
    *(short8*)(Wb + frag * 512 + ln * 8) = v;
  } else {
    __shared__ float pe[17 * 64];
    for (int idx = tid; idx < 17 * 64; idx += 256) pe[idx] = pos_emb[idx];
    __syncthreads();
    const int d = tid;
    float w[64];
    const float* wr = W1 + d * kInDim + 512;
#pragma unroll
    for (int q = 0; q < 16; ++q) {
      float4 t4 = *(const float4*)(wr + q * 4);
      w[q * 4 + 0] = t4.x; w[q * 4 + 1] = t4.y;
      w[q * 4 + 2] = t4.z; w[q * 4 + 3] = t4.w;
    }
    float acc[17];
#pragma unroll
    for (int t = 0; t < 17; ++t) acc[t] = 0.f;
    for (int u = 0; u < 17; ++u) {
      float m = 0.f;
#pragma unroll
      for (int p = 0; p < 64; ++p) m += pe[u * 64 + p] * w[p];
      int au = u - kK; if (au < 0) au = -au;
      m *= (float)(kS - au);
#pragma unroll
      for (int t = 0; t < 17; ++t) {
        int dd = t - u;
        acc[t] += expf((float)(-(dd * dd))) * m;
      }
    }
#pragma unroll
    for (int t = 0; t < 17; ++t) Rg[t * kD + d] = acc[t] + b1[d];
  }
}

// ---------------------------------------------------------------------------
// fused: 512 blocks (b = blk>>4, i0 = (blk&15)*8) x 512 threads = 8 waves;
// ~67KB LDS -> 2 blocks/CU -> 16 waves/CU. NO min-waves launch bound (R10's
// 64-VGPR spill lesson). TWO barriers total.
//  phase0: stage 32-row H window (f2b, row-XOR-swizzled) + sR from Rg
//  phase1: GEMM C[32][512] = sH x Wcat^T; A from LDS, B as coalesced 1KB
//          fragment bursts from Wb; 64 MFMA/wave -> sU/sV
//  phase2: pair scores (32 x 16-lane groups, 4-5 t-slots each)
// ---------------------------------------------------------------------------
__global__ __launch_bounds__(512) void fused(
    const float* __restrict__ H, const ushort* __restrict__ Wb,
    const float* __restrict__ Rg,
    const float* __restrict__ ln_g, const float* __restrict__ ln_b,
    const float* __restrict__ W2, const float* __restrict__ b2,
    float* __restrict__ out) {
  __shared__ __align__(16) ushort sH[32 * 256];   // 16 KB bf16, XOR-swizzled
  __shared__ float sR[17 * kRS];                  // 17.7 KB
  __shared__ float sU[8 * kRS];                   // 8.3 KB
  __shared__ float sV[24 * kRS];                  // 25 KB

  const int tid = threadIdx.x;
  const int lane = tid & 63;
  const int w = tid >> 6;            // wave 0..7
  const int b = blockIdx.x >> 4;
  const int i0 = (blockIdx.x & 15) << 3;
  const int ws = (i0 - 8 > 0) ? (i0 - 8) : 0;   // window start (mult of 8)
  const int oi = i0 - ws;                        // 0 or 8

  // ---- phase 0: stage H window (32 rows, row-index clamped) + sR ----
#pragma unroll
  for (int l = 0; l < 4; ++l) {
    const int idx = tid + l * 512;               // 0..2047
    const int rw = idx >> 6, kq = (idx & 63) << 2;
    int rg = ws + rw; if (rg > kS - 1) rg = kS - 1;
    float4 a = *(const float4*)(H + (b * kS + rg) * kD + kq);
    ushort4 u; u.x = f2b(a.x); u.y = f2b(a.y); u.z = f2b(a.z); u.w = f2b(a.w);
    *(ushort4*)&sH[rw * 256 + (kq ^ ((rw & 7) << 3))] = u;
  }
  for (int idx = tid; idx < 1088; idx += 512) {  // 17*256/4 float4-chunks
    float4 a = *(const float4*)(Rg + idx * 4);
    const int t = idx >> 6, d = (idx & 63) << 2;
    *(float4*)&sR[t * kRS + d] = a;
  }
  __syncthreads();

  // ---- phase 1: GEMM C[32][512]; wave w -> cols [w*64, w*64+64) ----
  {
    const int lr = lane & 15;
    const int lk = (lane >> 4) << 3;
    const int swz = (lr & 7) << 3;
    f32x4 acc[2][4] = {{{0,0,0,0},{0,0,0,0},{0,0,0,0},{0,0,0,0}},
                       {{0,0,0,0},{0,0,0,0},{0,0,0,0},{0,0,0,0}}};
#pragma unroll
    for (int kk = 0; kk < 8; ++kk) {
      const int k0 = (kk << 5) + lk;
      short8 a0 = *(const short8*)(const void*)&sH[lr * 256 + (k0 ^ swz)];
      short8 a1 = *(const short8*)(const void*)&sH[(16 + lr) * 256 + (k0 ^ swz)];
#pragma unroll
      for (int ci = 0; ci < 4; ++ci) {
        const int ct = (w << 2) + ci;
        short8 bf = *(const short8*)(const void*)(Wb + (ct * 8 + kk) * 512 + lane * 8);
        acc[0][ci] = __builtin_amdgcn_mfma_f32_16x16x32_bf16(a0, bf, acc[0][ci], 0, 0, 0);
        acc[1][ci] = __builtin_amdgcn_mfma_f32_16x16x32_bf16(a1, bf, acc[1][ci], 0, 0, 0);
      }
    }
    const int r0 = (lane >> 4) << 2;
#pragma unroll
    for (int m = 0; m < 2; ++m)
#pragma unroll
      for (int ci = 0; ci < 4; ++ci) {
        const int cg = ((w << 2) + ci) * 16 + (lane & 15);
#pragma unroll
        for (int r = 0; r < 4; ++r) {
          const int rw = (m << 4) + r0 + r;      // window row 0..31
          const float val = acc[m][ci][r];
          if (cg < kD) {
            unsigned ur = (unsigned)(rw - oi);
            if (ur < 8u) sU[ur * kRS + cg] = val;
          } else if (rw < 24) {
            sV[rw * kRS + (cg - kD)] = val;
          }
        }
      }
  }
  __syncthreads();

  // ---- phase 2: pair scores. group g: ir = g>>2, t-quarter qq = g&3 ----
  const int g = tid >> 4, l16 = tid & 15;
  const int ir = g >> 2, qq = g & 3;
  const int tb = qq * 4 + (qq > 0);     // 0,5,9,13
  const int te = qq * 4 + 5;            // 5,9,13,17
  const int i = i0 + ir;

  float ureg[16];
#pragma unroll
  for (int q = 0; q < 4; ++q) {
    float4 u4 = *(const float4*)&sU[ir * kRS + (q << 6) + (l16 << 2)];
    ureg[q * 4 + 0] = u4.x; ureg[q * 4 + 1] = u4.y;
    ureg[q * 4 + 2] = u4.z; ureg[q * 4 + 3] = u4.w;
  }
  float4 Gp[4], Bp[4], Wp[4];
#pragma unroll
  for (int q = 0; q < 4; ++q) {
    const int d = (q << 6) + (l16 << 2);
    Gp[q] = *(const float4*)(ln_g + d);
    Bp[q] = *(const float4*)(ln_b + d);
    Wp[q] = *(const float4*)(W2 + d);
  }
  const float bias2 = b2[0];

  int start_i;
  if (i <= 8)        start_i = (i * i + 17 * i) / 2;
  else if (i <= 120) start_i = 100 + (i - 8) * 17;
  else { int mm = i - 120; start_i = 2004 + 16 * mm - (mm * (mm - 1)) / 2; }
  const int lower = (i - kK > 0) ? (i - kK) : 0;

  for (int t = tb; t < te; ++t) {
    const int j = i - kK + t;
    if (j < 0 || j >= kS) continue;     // group-uniform
    const int p = start_i + (j - lower);
    const float* Vr = &sV[(j - ws) * kRS];
    const float* Rr = &sR[t * kRS];

    float h[16]; float ssum = 0.f, qsum = 0.f;
#pragma unroll
    for (int q = 0; q < 4; ++q) {
      const int d = (q << 6) + (l16 << 2);
      float4 v4 = *(const float4*)(Vr + d);
      float4 r4 = *(const float4*)(Rr + d);
      float h0 = ureg[q * 4 + 0] + v4.x + r4.x;
      float h1 = ureg[q * 4 + 1] + v4.y + r4.y;
      float h2 = ureg[q * 4 + 2] + v4.z + r4.z;
      float h3 = ureg[q * 4 + 3] + v4.w + r4.w;
      h[q * 4 + 0] = h0; h[q * 4 + 1] = h1; h[q * 4 + 2] = h2; h[q * 4 + 3] = h3;
      ssum += h0 + h1 + h2 + h3;
      qsum += h0 * h0 + h1 * h1 + h2 * h2 + h3 * h3;
    }
#pragma unroll
    for (int off = 8; off > 0; off >>= 1) {
      ssum += __shfl_xor(ssum, off);
      qsum += __shfl_xor(qsum, off);
    }
    const float mu = ssum * (1.0f / kD);
    const float var = qsum * (1.0f / kD) - mu * mu;
    const float rs = rsqrtf(var + 1e-5f);
    float dot = 0.f;
#pragma unroll
    for (int q = 0; q < 4; ++q) {
      float y0 = (h[q * 4 + 0] - mu) * rs * Gp[q].x + Bp[q].x;
      float y1 = (h[q * 4 + 1] - mu) * rs * Gp[q].y + Bp[q].y;
      float y2 = (h[q * 4 + 2] - mu) * rs * Gp[q].z + Bp[q].z;
      float y3 = (h[q * 4 + 3] - mu) * rs * Gp[q].w + Bp[q].w;
      y0 = y0 > 0.f ? y0 : (__expf(y0) - 1.0f);   // elu (alpha=1)
      y1 = y1 > 0.f ? y1 : (__expf(y1) - 1.0f);
      y2 = y2 > 0.f ? y2 : (__expf(y2) - 1.0f);
      y3 = y3 > 0.f ? y3 : (__expf(y3) - 1.0f);
      dot += y0 * Wp[q].x + y1 * Wp[q].y + y2 * Wp[q].z + y3 * Wp[q].w;
    }
#pragma unroll
    for (int off = 8; off > 0; off >>= 1) dot += __shfl_xor(dot, off);

    if (l16 == 0) {
      out[b * kNPair + p] = dot + bias2;
      if (b == 0) {
        float* po = out + kB * kNPair;  // positions read back as f32
        po[2 * p + 0] = (float)(i + 1);
        po[2 * p + 1] = (float)(j + 1);
      }
    }
  }
}

// ---------------------------------------------------------------------------
extern "C" void kernel_launch(void* const* d_in, const int* in_sizes, int n_in,
                              void* d_out, int out_size, void* d_ws, size_t ws_size,
                              hipStream_t stream) {
  (void)in_sizes; (void)n_in; (void)ws_size; (void)out_size;
  const float* H       = (const float*)d_in[0];  // [32,128,256]
  const float* pos_emb = (const float*)d_in[1];  // [17,64]
  const float* W1      = (const float*)d_in[2];  // [256,576]
  const float* b1      = (const float*)d_in[3];  // [256]
  const float* ln_g    = (const float*)d_in[4];  // [256]
  const float* ln_b    = (const float*)d_in[5];  // [256]
  const float* W2      = (const float*)d_in[6];  // [1,256]
  const float* b2      = (const float*)d_in[7];  // [1]
  float* out = (float*)d_out;

  ushort* Wb = (ushort*)d_ws;                    // [32][8][64][8] bf16, 256 KB
  float*  Rg = (float*)(Wb + 32 * 8 * 512);      // [17][256] f32

  prep<<<65, 256, 0, stream>>>(W1, pos_emb, b1, Wb, Rg);
  fused<<<kB * 16, 512, 0, stream>>>(H, Wb, Rg, ln_g, ln_b, W2, b2, out);
}